// Round 2
// baseline (89.321 us; speedup 1.0000x reference)
//
#include <hip/hip_runtime.h>

#define B 512
#define N 128
#define NG (N / 4)   // 32 groups of 4 points (12 floats = 3 float4)
#define TI 2         // i-rows per block

// Sum of 4 Euclidean distances for points packed as 3 float4 (12 floats = 4 x (x,y,z))
__device__ __forceinline__ float dist4(const float4 a0, const float4 a1, const float4 a2,
                                       const float4 b0, const float4 b1, const float4 b2) {
    float dx, dy, dz, s, r;
    dx = a0.x - b0.x; dy = a0.y - b0.y; dz = a0.z - b0.z;
    s = dx * dx + dy * dy + dz * dz; r = sqrtf(s);
    dx = a0.w - b0.w; dy = a1.x - b1.x; dz = a1.y - b1.y;
    s = dx * dx + dy * dy + dz * dz; r += sqrtf(s);
    dx = a1.z - b1.z; dy = a1.w - b1.w; dz = a2.x - b2.x;
    s = dx * dx + dy * dy + dz * dz; r += sqrtf(s);
    dx = a2.y - b2.y; dy = a2.z - b2.z; dz = a2.w - b2.w;
    s = dx * dx + dy * dy + dz * dz; r += sqrtf(s);
    return r;
}

__global__ __launch_bounds__(512) void vmse_kernel(const float* __restrict__ pred,
                                                   const float* __restrict__ gt,
                                                   const float* __restrict__ w,
                                                   const float* __restrict__ sigma,
                                                   float* __restrict__ out) {
    __shared__ __align__(16) float spred[TI * N * 3];  // 2 pred rows, 3 KB
    __shared__ float lbuf[TI][B];                      // logits rows, 4 KB
    __shared__ float wred[2][TI][8];                   // per-wave partials

    const int t = threadIdx.x;
    const int i0 = blockIdx.x * TI;

    // Stage the block's TI pred rows (contiguous 768 floats) into LDS, coalesced.
    {
        const float4* psrc = (const float4*)(pred + (size_t)i0 * (N * 3));
        float4* pdst = (float4*)spred;
        if (t < (TI * N * 3) / 4) pdst[t] = psrc[t];  // 192 float4
    }
    __syncthreads();

    const float nv = sigma[0] * sigma[0];

    // Each thread owns gt row j = t.
    const int j = t;
    const float4* grow = (const float4*)(gt + (size_t)j * (N * 3));
    const float4* prow0 = (const float4*)(spred);
    const float4* prow1 = (const float4*)(spred + N * 3);

    float acc0 = 0.f, acc1 = 0.f;
#pragma unroll 2
    for (int g = 0; g < NG; ++g) {
        const float4 g0 = grow[3 * g + 0];
        const float4 g1 = grow[3 * g + 1];
        const float4 g2 = grow[3 * g + 2];
        const float4 p00 = prow0[3 * g + 0];
        const float4 p01 = prow0[3 * g + 1];
        const float4 p02 = prow0[3 * g + 2];
        const float4 p10 = prow1[3 * g + 0];
        const float4 p11 = prow1[3 * g + 1];
        const float4 p12 = prow1[3 * g + 2];
        acc0 += dist4(g0, g1, g2, p00, p01, p02);
        acc1 += dist4(g0, g1, g2, p10, p11, p12);
    }

    const float norm0 = acc0 * (1.f / N);
    const float norm1 = acc1 * (1.f / N);
    float l0 = -0.5f * norm0 * norm0 / nv;
    float l1 = -0.5f * norm1 * norm1 / nv;
    lbuf[0][j] = l0;
    lbuf[1][j] = l1;

    // --- row-wise logsumexp over 512 values (one per thread), both rows at once ---
    float m0 = l0, m1 = l1;
    for (int off = 32; off; off >>= 1) {
        m0 = fmaxf(m0, __shfl_xor(m0, off));
        m1 = fmaxf(m1, __shfl_xor(m1, off));
    }
    const int wid = t >> 6, lane = t & 63;
    if (lane == 0) { wred[0][0][wid] = m0; wred[0][1][wid] = m1; }
    __syncthreads();

    float rm0 = -1e30f, rm1 = -1e30f;
#pragma unroll
    for (int k = 0; k < 8; ++k) {
        rm0 = fmaxf(rm0, wred[0][0][k]);
        rm1 = fmaxf(rm1, wred[0][1][k]);
    }

    float e0 = __expf(l0 - rm0), e1 = __expf(l1 - rm1);
    for (int off = 32; off; off >>= 1) {
        e0 += __shfl_xor(e0, off);
        e1 += __shfl_xor(e1, off);
    }
    if (lane == 0) { wred[1][0][wid] = e0; wred[1][1][wid] = e1; }
    __syncthreads();

    if (t == 0) {
        float s0 = 0.f, s1 = 0.f;
#pragma unroll
        for (int k = 0; k < 8; ++k) { s0 += wred[1][0][k]; s1 += wred[1][1][k]; }
        const float lse0 = rm0 + __logf(s0);
        const float lse1 = rm1 + __logf(s1);
        const float d0 = lbuf[0][i0];      // logits[i0][i0]
        const float d1 = lbuf[1][i0 + 1];  // logits[i0+1][i0+1]
        out[i0]     = (lse0 - d0) * 2.f * nv * w[i0];
        out[i0 + 1] = (lse1 - d1) * 2.f * nv * w[i0 + 1];
    }
}

extern "C" void kernel_launch(void* const* d_in, const int* in_sizes, int n_in,
                              void* d_out, int out_size, void* d_ws, size_t ws_size,
                              hipStream_t stream) {
    const float* pred  = (const float*)d_in[0];
    const float* gt    = (const float*)d_in[1];
    const float* wts   = (const float*)d_in[2];
    const float* sigma = (const float*)d_in[3];
    float* out = (float*)d_out;

    hipLaunchKernelGGL(vmse_kernel, dim3(B / TI), dim3(512), 0, stream,
                       pred, gt, wts, sigma, out);
}

// Round 4
// 86.905 us; speedup vs baseline: 1.0278x; 1.0278x over previous
//
#include <hip/hip_runtime.h>

#define B 512
#define N 128
#define NQ 96   // float4s per row (N*3/4)
#define TI 2    // pred rows per block

// Sum of 4 Euclidean distances for points packed as 3 float4 (12 floats = 4 x (x,y,z))
__device__ __forceinline__ float dist4(const float4 a0, const float4 a1, const float4 a2,
                                       const float4 b0, const float4 b1, const float4 b2) {
    float dx, dy, dz, s, r;
    dx = a0.x - b0.x; dy = a0.y - b0.y; dz = a0.z - b0.z;
    s = dx * dx + dy * dy + dz * dz; r = sqrtf(s);
    dx = a0.w - b0.w; dy = a1.x - b1.x; dz = a1.y - b1.y;
    s = dx * dx + dy * dy + dz * dz; r += sqrtf(s);
    dx = a1.z - b1.z; dy = a1.w - b1.w; dz = a2.x - b2.x;
    s = dx * dx + dy * dy + dz * dz; r += sqrtf(s);
    dx = a2.y - b2.y; dy = a2.z - b2.z; dz = a2.w - b2.w;
    s = dx * dx + dy * dy + dz * dz; r += sqrtf(s);
    return r;
}

// Kernel 1: gtT[q][j] = gt[j][q]  (float4 granularity). Coalesced read, scattered write
// (writes land in L2; total 768 KB, negligible).
__global__ __launch_bounds__(256) void transpose_gt(const float4* __restrict__ gt4,
                                                    float4* __restrict__ gtT) {
    const int tid = blockIdx.x * 256 + threadIdx.x;  // 0 .. 49151
    const int j = tid / NQ;
    const int q = tid - j * NQ;
    gtT[q * B + j] = gt4[tid];
}

// Kernel 2: fused pairwise-distance + row logsumexp + diagonal CE loss.
// Thread t owns gt row j=t (now coalesced via gtT); pred rows are wave-uniform
// -> scalar (s_load) path, no LDS staging.
__global__ __launch_bounds__(512) void vmse_main(const float* __restrict__ pred,
                                                 const float4* __restrict__ gtT,
                                                 const float* __restrict__ w,
                                                 const float* __restrict__ sigma,
                                                 float* __restrict__ out) {
    __shared__ float sdiag[TI];
    __shared__ float wred[2][TI][8];

    const int t = threadIdx.x;
    const int i0 = blockIdx.x * TI;

    // Wave-uniform pred row pointers: compiler emits scalar loads (constant cache).
    const float4* p0 = (const float4*)(pred + (size_t)i0 * (N * 3));
    const float4* p1 = p0 + NQ;

    float acc0 = 0.f, acc1 = 0.f;
#pragma unroll 4
    for (int g = 0; g < 32; ++g) {
        const float4 g0 = gtT[(3 * g + 0) * B + t];   // lane-stride 16B: coalesced
        const float4 g1 = gtT[(3 * g + 1) * B + t];
        const float4 g2 = gtT[(3 * g + 2) * B + t];
        const float4 a0 = p0[3 * g + 0];
        const float4 a1 = p0[3 * g + 1];
        const float4 a2 = p0[3 * g + 2];
        const float4 b0 = p1[3 * g + 0];
        const float4 b1 = p1[3 * g + 1];
        const float4 b2 = p1[3 * g + 2];
        acc0 += dist4(g0, g1, g2, a0, a1, a2);
        acc1 += dist4(g0, g1, g2, b0, b1, b2);
    }

    const float nv = sigma[0] * sigma[0];
    const float c = -0.5f / nv;
    const float n0 = acc0 * (1.f / N);
    const float n1 = acc1 * (1.f / N);
    const float l0 = n0 * n0 * c;   // logits[i0][t]
    const float l1 = n1 * n1 * c;   // logits[i0+1][t]

    if (t == i0)     sdiag[0] = l0;  // diagonal elements
    if (t == i0 + 1) sdiag[1] = l1;

    // --- row-wise logsumexp over 512 values (one per thread), both rows at once ---
    float m0 = l0, m1 = l1;
    for (int off = 32; off; off >>= 1) {
        m0 = fmaxf(m0, __shfl_xor(m0, off));
        m1 = fmaxf(m1, __shfl_xor(m1, off));
    }
    const int wid = t >> 6, lane = t & 63;
    if (lane == 0) { wred[0][0][wid] = m0; wred[0][1][wid] = m1; }
    __syncthreads();

    float rm0 = -1e30f, rm1 = -1e30f;
#pragma unroll
    for (int k = 0; k < 8; ++k) {
        rm0 = fmaxf(rm0, wred[0][0][k]);
        rm1 = fmaxf(rm1, wred[0][1][k]);
    }

    float e0 = __expf(l0 - rm0), e1 = __expf(l1 - rm1);
    for (int off = 32; off; off >>= 1) {
        e0 += __shfl_xor(e0, off);
        e1 += __shfl_xor(e1, off);
    }
    if (lane == 0) { wred[1][0][wid] = e0; wred[1][1][wid] = e1; }
    __syncthreads();

    if (t == 0) {
        float s0 = 0.f, s1 = 0.f;
#pragma unroll
        for (int k = 0; k < 8; ++k) { s0 += wred[1][0][k]; s1 += wred[1][1][k]; }
        const float lse0 = rm0 + __logf(s0);
        const float lse1 = rm1 + __logf(s1);
        out[i0]     = (lse0 - sdiag[0]) * 2.f * nv * w[i0];
        out[i0 + 1] = (lse1 - sdiag[1]) * 2.f * nv * w[i0 + 1];
    }
}

extern "C" void kernel_launch(void* const* d_in, const int* in_sizes, int n_in,
                              void* d_out, int out_size, void* d_ws, size_t ws_size,
                              hipStream_t stream) {
    const float* pred  = (const float*)d_in[0];
    const float* gt    = (const float*)d_in[1];
    const float* wts   = (const float*)d_in[2];
    const float* sigma = (const float*)d_in[3];
    float* out = (float*)d_out;
    float4* gtT = (float4*)d_ws;   // 96*512*16B = 768 KB scratch

    hipLaunchKernelGGL(transpose_gt, dim3((B * NQ) / 256), dim3(256), 0, stream,
                       (const float4*)gt, gtT);
    hipLaunchKernelGGL(vmse_main, dim3(B / TI), dim3(512), 0, stream,
                       pred, gtT, wts, sigma, out);
}